// Round 2
// baseline (611.878 us; speedup 1.0000x reference)
//
#include <hip/hip_runtime.h>
#include <hip/hip_bf16.h>

// FourierLayer2dLite on gfx950.
// B=16, M=N=256, I=O=64, NM=16.
// Only modes kx in {0..15, 240..255} (index a: kx = a<16 ? a : 224+a), ky in [0,16)
// survive, so both FFTs are replaced by partial direct DFTs (separable passes).
//
// Pipeline (all on stream, ws scratch):
//   k_wt : wT[ky][a][i][o] (float2)   <- fw1/fw2 transpose (coalesced both sides)
//   k1   : T[b][ky][m][i]  = (1/256) sum_n x[b,m,n,i] e^{-2pi i ky n/256}
//   k2   : X[b][ky][a][i]  = sum_m T e^{-2pi i kx_a m/256}          (= x_ft modes)
//   k3   : OF[b][ky][a][o] = sum_i X * w[i,o,a,ky]                  (= out_ft)
//   k4   : G[b][u][ky][o]  = c_ky*SC2 * sum_a OF e^{+2pi i kx_a u/256}
//   k5   : y[v][o] = sum_ky Re(G e^{+2pi i ky v/256});  out = relu(yW + b + y), f32
// SC2 = sqrt(256*129)/65536 (irfft2 1/N^2 + TF rescale); 1/256 fwd norm in k1.
// c2r ignores Im of ky=0 bin: handled since sin(0)=0 contribution (only gre[0] used).
// OUTPUT IS FLOAT32 (reference returns f32; round-1 failure was bf16 stores).

#define PI2F 6.283185307179586f

static __device__ __forceinline__ float bf16_to_f(unsigned short h) {
  union { unsigned int u; float f; } v; v.u = ((unsigned int)h) << 16; return v.f;
}
static __device__ __forceinline__ unsigned short f_to_bf16(float f) {
  unsigned int u = __float_as_uint(f);
  u += 0x7fffu + ((u >> 16) & 1u);   // RNE (values are finite)
  return (unsigned short)(u >> 16);
}

// ---------------- K0: weight transpose ----------------
// grid 256 = 32 a * 8 i-chunks, 256 thr
__global__ __launch_bounds__(256) void k_wt(const float* __restrict__ fw1,
                                            const float* __restrict__ fw2,
                                            float2* __restrict__ wT) {
  int a  = blockIdx.x >> 3;
  int ic = blockIdx.x & 7;
  const float* w = (a < 16) ? fw1 : fw2;
  int xx = a & 15;
#pragma unroll
  for (int k = 0; k < 2; ++k) {
    int p = k * 256 + (int)threadIdx.x;       // 512 (i_local,o) pairs
    int i = ic * 8 + (p >> 6);
    int o = p & 63;
    const float4* s4 = reinterpret_cast<const float4*>(
        w + ((((size_t)i * 64 + o) * 16 + xx) * 16) * 2);
#pragma unroll
    for (int j = 0; j < 8; ++j) {
      float4 q = s4[j];                        // y = 2j, 2j+1 (re,im interleaved)
      wT[(((size_t)(2 * j) * 32 + a) * 64 + i) * 64 + o]     = make_float2(q.x, q.y);
      wT[(((size_t)(2 * j + 1) * 32 + a) * 64 + i) * 64 + o] = make_float2(q.z, q.w);
    }
  }
}

// ---------------- K1: forward DFT over n ----------------
// grid 4096 = (b,m), 64 thr: thread = (i-chunk of 16, ky); rotation recurrence.
__global__ __launch_bounds__(64) void k1_fwd_n(const float* __restrict__ x,
                                               float* __restrict__ T) {
  int bm = blockIdx.x;                 // b*256 + m
  int b = bm >> 8, m = bm & 255;
  int lane = threadIdx.x;
  int ib = (lane & 3) * 16;            // 16 consecutive i
  int ky = lane >> 2;                  // 0..15
  const float* xp = x + (size_t)bm * 16384 + ib;

  float sd, cd;
  sincosf(PI2F * (float)ky * (1.0f / 256.0f), &sd, &cd);
  float mulc = cd, muls = -sd;         // e^{-2pi i ky/256}
  float c = 1.0f, s = 0.0f;

  float are[16], aim[16];
#pragma unroll
  for (int ii = 0; ii < 16; ++ii) { are[ii] = 0.0f; aim[ii] = 0.0f; }

  for (int n = 0; n < 256; ++n) {
    const float4* xv = reinterpret_cast<const float4*>(xp + (size_t)n * 64);
    float4 v0 = xv[0], v1 = xv[1], v2 = xv[2], v3 = xv[3];
    float vv[16] = {v0.x, v0.y, v0.z, v0.w, v1.x, v1.y, v1.z, v1.w,
                    v2.x, v2.y, v2.z, v2.w, v3.x, v3.y, v3.z, v3.w};
#pragma unroll
    for (int ii = 0; ii < 16; ++ii) {
      are[ii] = __builtin_fmaf(vv[ii], c, are[ii]);
      aim[ii] = __builtin_fmaf(vv[ii], s, aim[ii]);
    }
    float cn = c * mulc - s * muls;
    s = c * muls + s * mulc;
    c = cn;
  }

  const float SC = 1.0f / 256.0f;      // forward rfft2 normalization
  float* Tp = T + (((size_t)(b * 16 + ky) * 256 + m) * 64 + ib) * 2;
#pragma unroll
  for (int ii = 0; ii < 16; ii += 2) {
    float4 o4 = make_float4(are[ii] * SC, aim[ii] * SC, are[ii + 1] * SC, aim[ii + 1] * SC);
    reinterpret_cast<float4*>(Tp)[ii >> 1] = o4;
  }
}

// ---------------- K2: forward DFT over m onto 32 kx modes ----------------
// grid 256 = (b,ky), 256 thr: thread = (i-chunk of 4, a-pair {ag, ag+16})
__global__ __launch_bounds__(256) void k2_fwd_m(const float* __restrict__ T,
                                                float* __restrict__ X) {
  int bky = blockIdx.x;                // b*16 + ky
  int ih = threadIdx.x & 15;
  int ag = threadIdx.x >> 4;           // 0..15
  const float* Tp = T + (size_t)bky * 32768 + ih * 8;

  float cd1, sd1n, cd2, sd2n;
  { float ss, cc; sincosf(PI2F * (float)ag * (1.0f / 256.0f), &ss, &cc); cd1 = cc; sd1n = -ss; }
  { float ss, cc; sincosf(PI2F * (float)(ag - 16) * (1.0f / 256.0f), &ss, &cc); cd2 = cc; sd2n = -ss; }
  float c1 = 1.0f, s1 = 0.0f, c2 = 1.0f, s2 = 0.0f;

  float xr1[4], xi1[4], xr2[4], xi2[4];
#pragma unroll
  for (int ii = 0; ii < 4; ++ii) { xr1[ii] = xi1[ii] = xr2[ii] = xi2[ii] = 0.0f; }

#pragma unroll 4
  for (int m = 0; m < 256; ++m) {
    const float4* tp4 = reinterpret_cast<const float4*>(Tp + (size_t)m * 128);
    float4 t0 = tp4[0], t1 = tp4[1];
    float tre[4] = {t0.x, t0.z, t1.x, t1.z};
    float tim[4] = {t0.y, t0.w, t1.y, t1.w};
#pragma unroll
    for (int ii = 0; ii < 4; ++ii) {
      xr1[ii] += tre[ii] * c1 - tim[ii] * s1;
      xi1[ii] += tre[ii] * s1 + tim[ii] * c1;
      xr2[ii] += tre[ii] * c2 - tim[ii] * s2;
      xi2[ii] += tre[ii] * s2 + tim[ii] * c2;
    }
    float cn;
    cn = c1 * cd1 - s1 * sd1n; s1 = c1 * sd1n + s1 * cd1; c1 = cn;
    cn = c2 * cd2 - s2 * sd2n; s2 = c2 * sd2n + s2 * cd2; c2 = cn;
  }

  float* Xp1 = X + ((size_t)bky * 32 + ag) * 128 + ih * 8;
  float* Xp2 = X + ((size_t)bky * 32 + ag + 16) * 128 + ih * 8;
  reinterpret_cast<float4*>(Xp1)[0] = make_float4(xr1[0], xi1[0], xr1[1], xi1[1]);
  reinterpret_cast<float4*>(Xp1)[1] = make_float4(xr1[2], xi1[2], xr1[3], xi1[3]);
  reinterpret_cast<float4*>(Xp2)[0] = make_float4(xr2[0], xi2[0], xr2[1], xi2[1]);
  reinterpret_cast<float4*>(Xp2)[1] = make_float4(xr2[2], xi2[2], xr2[3], xi2[3]);
}

// ---------------- K3: mode mix over i ----------------
// grid 512 = (ky,a), 256 thr; w slice staged in LDS (split re/im, pad 65), loop b.
__global__ __launch_bounds__(256) void k3_mix(const float* __restrict__ Xg,
                                              const float* __restrict__ wT,
                                              float* __restrict__ OF) {
  int blk = blockIdx.x;
  int kyy = blk >> 5, a = blk & 31;
  __shared__ float wre[64 * 65];
  __shared__ float wim[64 * 65];
  __shared__ float xsh[16 * 128];

  const float2* wsrc = reinterpret_cast<const float2*>(wT) + (size_t)(kyy * 32 + a) * 4096;
#pragma unroll
  for (int k = 0; k < 16; ++k) {
    int p = k * 256 + (int)threadIdx.x;      // p = i*64 + o
    float2 v = wsrc[p];
    int i = p >> 6, o = p & 63;
    wre[i * 65 + o] = v.x;
    wim[i * 65 + o] = v.y;
  }
  {
    int bb = threadIdx.x >> 4, icn = threadIdx.x & 15;
    const float4* xsrc = reinterpret_cast<const float4*>(
        Xg + ((size_t)(bb * 16 + kyy) * 32 + a) * 128);
    float4* xdst = reinterpret_cast<float4*>(xsh + bb * 128);
    xdst[icn * 2]     = xsrc[icn * 2];
    xdst[icn * 2 + 1] = xsrc[icn * 2 + 1];
  }
  __syncthreads();

  int o = threadIdx.x & 63, bg = threadIdx.x >> 6;
#pragma unroll
  for (int bb = 0; bb < 4; ++bb) {
    int b = bg * 4 + bb;
    float ore = 0.0f, oim = 0.0f;
    for (int i = 0; i < 64; ++i) {
      float xr = xsh[b * 128 + 2 * i], xi = xsh[b * 128 + 2 * i + 1];
      float wr = wre[i * 65 + o],     wi = wim[i * 65 + o];
      ore += xr * wr - xi * wi;
      oim += xr * wi + xi * wr;
    }
    reinterpret_cast<float2*>(OF)[(((size_t)b * 16 + kyy) * 32 + a) * 64 + o] =
        make_float2(ore, oim);
  }
}

// ---------------- K4: inverse DFT over kx (all u), fold c_ky & scale ----------------
// grid 256 = (b, u-group of 16), 256 thr; OF staged in 4 ky-chunks of 64KB.
__global__ __launch_bounds__(256) void k4_inv_kx(const float* __restrict__ OF,
                                                 float* __restrict__ G) {
  int blk = blockIdx.x;
  int b = blk >> 4, ug = blk & 15;
  __shared__ float ofs[16384];         // [4ky][32a][64o] float2
  __shared__ float ct[256], st[256];
  {
    float ssv, ccv;
    sincosf(PI2F * (float)threadIdx.x * (1.0f / 256.0f), &ssv, &ccv);
    ct[threadIdx.x] = ccv;
    st[threadIdx.x] = ssv;
  }
  int o = threadIdx.x & 63, us = threadIdx.x >> 6;
  int u0 = ug * 16 + us * 4;
  const float SC2 = 0.002772904280510622f;   // sqrt(256*129)/65536

  for (int chunk = 0; chunk < 4; ++chunk) {
    __syncthreads();
    const float4* src = reinterpret_cast<const float4*>(
        OF + (size_t)(b * 16 + chunk * 4) * 4096);
    float4* dst = reinterpret_cast<float4*>(ofs);
#pragma unroll
    for (int k = 0; k < 16; ++k) dst[k * 256 + threadIdx.x] = src[k * 256 + threadIdx.x];
    __syncthreads();

    float accr[4][4], acci[4][4];
#pragma unroll
    for (int du = 0; du < 4; ++du)
#pragma unroll
      for (int kyl = 0; kyl < 4; ++kyl) { accr[du][kyl] = 0.0f; acci[du][kyl] = 0.0f; }

    for (int a = 0; a < 32; ++a) {
      int kx = (a < 16) ? a : (224 + a);
      float ofr[4], ofi[4];
#pragma unroll
      for (int kyl = 0; kyl < 4; ++kyl) {
        ofr[kyl] = ofs[((kyl * 32 + a) * 64 + o) * 2];
        ofi[kyl] = ofs[((kyl * 32 + a) * 64 + o) * 2 + 1];
      }
#pragma unroll
      for (int du = 0; du < 4; ++du) {
        int t = (kx * (u0 + du)) & 255;
        float cv = ct[t], sv = st[t];
#pragma unroll
        for (int kyl = 0; kyl < 4; ++kyl) {
          accr[du][kyl] += ofr[kyl] * cv - ofi[kyl] * sv;
          acci[du][kyl] += ofr[kyl] * sv + ofi[kyl] * cv;
        }
      }
    }
#pragma unroll
    for (int du = 0; du < 4; ++du) {
      int u = u0 + du;
#pragma unroll
      for (int kyl = 0; kyl < 4; ++kyl) {
        int ky = chunk * 4 + kyl;
        float sc = SC2 * ((ky == 0) ? 1.0f : 2.0f);
        reinterpret_cast<float2*>(G)[(((size_t)b * 256 + u) * 16 + ky) * 64 + o] =
            make_float2(accr[du][kyl] * sc, acci[du][kyl] * sc);
      }
    }
  }
}

// ---------------- K5: inverse over v (Chebyshev) + relu(yW + b + y) ----------------
// grid 4096 = (b,u), 256 thr. yT[o][v] in LDS as bf16 (stride 258, bank-clean).
// y magnitudes ~0.1-0.6 -> bf16 staging error ~5e-4, well under threshold.
__global__ __launch_bounds__(256) void k5_out(const float* __restrict__ G,
                                              const float* __restrict__ Wg,
                                              const float* __restrict__ bias,
                                              float* __restrict__ out) {
  int blk = blockIdx.x;
  int b = blk >> 8, u = blk & 255;
  __shared__ unsigned short yS[64 * 258];
  __shared__ float wS[64 * 66];

#pragma unroll
  for (int k = 0; k < 16; ++k) {
    int p = k * 256 + (int)threadIdx.x;
    wS[(p >> 6) * 66 + (p & 63)] = Wg[p];
  }

  int o = threadIdx.x & 63, vg = threadIdx.x >> 6;
  const float* gp = G + ((size_t)b * 256 + u) * 2048 + o * 2;
  float gre[16], gim[16];
#pragma unroll
  for (int ky = 0; ky < 16; ++ky) {
    gre[ky] = gp[ky * 128];
    gim[ky] = gp[ky * 128 + 1];
  }

  int v0 = vg * 64;
  float cp[15], cc[15], sp[15], scur[15], k2c[15];
#pragma unroll
  for (int kk = 0; kk < 15; ++kk) {
    float d = PI2F * (float)(kk + 1) * (1.0f / 256.0f);
    float sd, cdv; sincosf(d, &sd, &cdv);
    k2c[kk] = 2.0f * cdv;
    float th0 = d * (float)v0;
    float s0v, c0v; sincosf(th0, &s0v, &c0v);
    float sm, cm;  sincosf(th0 - d, &sm, &cm);
    cp[kk] = cm; cc[kk] = c0v; sp[kk] = sm; scur[kk] = s0v;
  }

  for (int vl = 0; vl < 64; ++vl) {
    float y = gre[0];
#pragma unroll
    for (int kk = 0; kk < 15; ++kk) {
      y += gre[kk + 1] * cc[kk] - gim[kk + 1] * scur[kk];
      float cn = __builtin_fmaf(k2c[kk], cc[kk], -cp[kk]); cp[kk] = cc[kk]; cc[kk] = cn;
      float sn = __builtin_fmaf(k2c[kk], scur[kk], -sp[kk]); sp[kk] = scur[kk]; scur[kk] = sn;
    }
    yS[o * 258 + v0 + vl] = f_to_bf16(y);
  }
  __syncthreads();

  int oq = threadIdx.x & 7, vq = threadIdx.x >> 3;   // 8 o' x 8 v (stride-32) tile
  float bv[8];
#pragma unroll
  for (int c = 0; c < 8; ++c) bv[c] = bias[oq * 8 + c];

  float acc[8][8];
#pragma unroll
  for (int r = 0; r < 8; ++r)
#pragma unroll
    for (int c = 0; c < 8; ++c) acc[r][c] = 0.0f;

  for (int oo = 0; oo < 64; ++oo) {
    float yv[8], wv[8];
#pragma unroll
    for (int r = 0; r < 8; ++r) yv[r] = bf16_to_f(yS[oo * 258 + vq + 32 * r]);
#pragma unroll
    for (int c = 0; c < 8; ++c) wv[c] = wS[oo * 66 + oq * 8 + c];
#pragma unroll
    for (int r = 0; r < 8; ++r)
#pragma unroll
      for (int c = 0; c < 8; ++c) acc[r][c] = __builtin_fmaf(yv[r], wv[c], acc[r][c]);
  }

#pragma unroll
  for (int r = 0; r < 8; ++r) {
    int v = vq + 32 * r;
    float res[8];
#pragma unroll
    for (int c = 0; c < 8; ++c) {
      float yo = bf16_to_f(yS[(oq * 8 + c) * 258 + v]);
      float z = acc[r][c] + bv[c] + yo;
      res[c] = fmaxf(z, 0.0f);
    }
    float* op = out + (((size_t)b * 256 + u) * 256 + v) * 64 + oq * 8;
    reinterpret_cast<float4*>(op)[0] = make_float4(res[0], res[1], res[2], res[3]);
    reinterpret_cast<float4*>(op)[1] = make_float4(res[4], res[5], res[6], res[7]);
  }
}

extern "C" void kernel_launch(void* const* d_in, const int* in_sizes, int n_in,
                              void* d_out, int out_size, void* d_ws, size_t ws_size,
                              hipStream_t stream) {
  const float* x   = (const float*)d_in[0];
  const float* fw1 = (const float*)d_in[1];
  const float* fw2 = (const float*)d_in[2];
  const float* W   = (const float*)d_in[3];
  const float* bb  = (const float*)d_in[4];
  float* out = (float*)d_out;         // reference output dtype is float32

  float* ws = (float*)d_ws;
  float* wT = ws;                     // 4,194,304 floats (16 MB)
  float* T  = ws + 4194304;           // 8,388,608 floats (32 MB)
  float* X  = ws + 12582912;          // 1,048,576 floats (4 MB)
  float* OF = ws + 13631488;          // 1,048,576 floats (4 MB)
  float* G  = T;                      // alias: T dead after k2, G written in k4

  hipLaunchKernelGGL(k_wt,     dim3(256),  dim3(256), 0, stream, fw1, fw2, (float2*)wT);
  hipLaunchKernelGGL(k1_fwd_n, dim3(4096), dim3(64),  0, stream, x, T);
  hipLaunchKernelGGL(k2_fwd_m, dim3(256),  dim3(256), 0, stream, T, X);
  hipLaunchKernelGGL(k3_mix,   dim3(512),  dim3(256), 0, stream, X, wT, OF);
  hipLaunchKernelGGL(k4_inv_kx,dim3(256),  dim3(256), 0, stream, OF, G);
  hipLaunchKernelGGL(k5_out,   dim3(4096), dim3(256), 0, stream, G, W, bb, out);
}

// Round 3
// 256.593 us; speedup vs baseline: 2.3846x; 2.3846x over previous
//
#include <hip/hip_runtime.h>
#include <hip/hip_bf16.h>

// FourierLayer2dLite on gfx950.  B=16, M=N=256, I=O=64, NM=16.
// Modes: kx in {0..15,240..255} (a: kx = a<16 ? a : 224+a), ky in [0,16).
// Pipeline:
//   k_tab: Eg[kc][n] bf16 (cos/-sin), CSg[v][kc] bf16 (cos/+sin) trig tables
//   k_wt : wT[ky][a][i][o] float2
//   k1m  : T[b][ky][m][i]x2 = (1/256) E[32x256] @ x[b,m,:,:]     (MFMA bf16)
//   k2   : X[b][ky][a][i]x2 = sum_m T e^{-2pi i kx_a m/256}       (fp32)
//   k3   : OF[b][ky][a][o]x2 = sum_i X * w                        (fp32)
//   k4   : G[b][u][ky][o]x2 = c_ky*SC2 * sum_a OF e^{+2pi i kx_a u/256} (fp32)
//   k5m  : Y = CS[256x32] @ G'[32x64];  OUT = relu(Y@W + b + Y)   (MFMA bf16)
// MFMA 16x16x32 bf16 layouts: A[m][k]: m=lane&15, k=(lane>>4)*8+j;
// B[k][n]: n=lane&15, k=(lane>>4)*8+j; C/D: col=lane&15, row=(lane>>4)*4+reg.

#define PI2F 6.283185307179586f

typedef __attribute__((ext_vector_type(8))) short short8v;
typedef __attribute__((ext_vector_type(4))) float f32x4;

static __device__ __forceinline__ float bf16_to_f(unsigned short h) {
  union { unsigned int u; float f; } v; v.u = ((unsigned int)h) << 16; return v.f;
}
static __device__ __forceinline__ unsigned short f_to_bf16(float f) {
  unsigned int u = __float_as_uint(f);
  u += 0x7fffu + ((u >> 16) & 1u);   // RNE (finite values)
  return (unsigned short)(u >> 16);
}

// ---------------- k_tab: trig tables (1 block) ----------------
// Eg[kc=2ky+c][n] : cos(2pi ky n/256), -sin(...)   (k1 A-operand)
// CSg[v][kc=2ky+c]: cos(2pi ky v/256), +sin(...)   (k5 A-operand)
__global__ __launch_bounds__(256) void k_tab(unsigned short* __restrict__ Eg,
                                             unsigned short* __restrict__ CSg) {
  int t = threadIdx.x;                // n or v
#pragma unroll
  for (int ky = 0; ky < 16; ++ky) {
    int idx = (ky * t) & 255;
    float ss, cc;
    sincosf(PI2F * (float)idx * (1.0f / 256.0f), &ss, &cc);
    Eg[(2 * ky) * 256 + t]     = f_to_bf16(cc);
    Eg[(2 * ky + 1) * 256 + t] = f_to_bf16(-ss);
    CSg[t * 32 + 2 * ky]       = f_to_bf16(cc);
    CSg[t * 32 + 2 * ky + 1]   = f_to_bf16(ss);
  }
}

// ---------------- K0: weight transpose ----------------
__global__ __launch_bounds__(256) void k_wt(const float* __restrict__ fw1,
                                            const float* __restrict__ fw2,
                                            float2* __restrict__ wT) {
  int a  = blockIdx.x >> 3;
  int ic = blockIdx.x & 7;
  const float* w = (a < 16) ? fw1 : fw2;
  int xx = a & 15;
#pragma unroll
  for (int k = 0; k < 2; ++k) {
    int p = k * 256 + (int)threadIdx.x;
    int i = ic * 8 + (p >> 6);
    int o = p & 63;
    const float4* s4 = reinterpret_cast<const float4*>(
        w + ((((size_t)i * 64 + o) * 16 + xx) * 16) * 2);
#pragma unroll
    for (int j = 0; j < 8; ++j) {
      float4 q = s4[j];
      wT[(((size_t)(2 * j) * 32 + a) * 64 + i) * 64 + o]     = make_float2(q.x, q.y);
      wT[(((size_t)(2 * j + 1) * 32 + a) * 64 + i) * 64 + o] = make_float2(q.z, q.w);
    }
  }
}

// ---------------- K1 (MFMA): T[b,ky,m,i] = (1/256) E @ x ----------------
// grid 4096 = (b,m), 256 thr = 4 waves. Wave w owns i-cols 16w..16w+15.
// B-operand (x) read straight from global: per-lane 8 n-strided f32 loads,
// each instr = 4 x 64B contiguous segments (coalesced). A (E) from LDS.
__global__ __launch_bounds__(256) void k1_mfma(const float* __restrict__ x,
                                               const unsigned short* __restrict__ Eg,
                                               float* __restrict__ T) {
  __shared__ unsigned short El[32 * 264];   // [kc][n], stride 264 (528B, 2-way banks)
  int bm = blockIdx.x;
  int b = bm >> 8, m = bm & 255;
  int tid = threadIdx.x;

  {
    const unsigned int* src = reinterpret_cast<const unsigned int*>(Eg);
    unsigned int* dst = reinterpret_cast<unsigned int*>(El);
#pragma unroll
    for (int t = 0; t < 16; ++t) {
      int idx = t * 256 + tid;              // dw index in [32][128]
      dst[(idx >> 7) * 132 + (idx & 127)] = src[idx];
    }
  }
  __syncthreads();

  int lane = tid & 63, w = tid >> 6;
  int r16 = lane & 15, g4 = lane >> 4;
  const float* xp = x + (size_t)bm * 16384 + (w * 16 + r16);

  f32x4 z = {0.f, 0.f, 0.f, 0.f};
  f32x4 acc0 = z, acc1 = z;

#pragma unroll
  for (int ks = 0; ks < 8; ++ks) {
    int nb = ks * 32 + g4 * 8;
    float xv[8];
#pragma unroll
    for (int j = 0; j < 8; ++j) xv[j] = xp[(size_t)(nb + j) * 64];
    short8v bfr;
#pragma unroll
    for (int j = 0; j < 8; ++j) bfr[j] = (short)f_to_bf16(xv[j]);
    short8v a0 = *reinterpret_cast<const short8v*>(&El[r16 * 264 + nb]);
    short8v a1 = *reinterpret_cast<const short8v*>(&El[(16 + r16) * 264 + nb]);
    acc0 = __builtin_amdgcn_mfma_f32_16x16x32_bf16(a0, bfr, acc0, 0, 0, 0);
    acc1 = __builtin_amdgcn_mfma_f32_16x16x32_bf16(a1, bfr, acc1, 0, 0, 0);
  }

  const float SC = 1.0f / 256.0f;
  int i = w * 16 + r16;
#pragma unroll
  for (int mt = 0; mt < 2; ++mt) {
    f32x4 av = (mt == 0) ? acc0 : acc1;
#pragma unroll
    for (int r = 0; r < 4; ++r) {
      int kc = mt * 16 + g4 * 4 + r;
      int ky = kc >> 1, cmp = kc & 1;
      T[(((size_t)(b * 16 + ky) * 256 + m) * 64 + i) * 2 + cmp] = av[r] * SC;
    }
  }
}

// ---------------- K2: forward DFT over m onto 32 kx modes (fp32) ----------------
__global__ __launch_bounds__(256) void k2_fwd_m(const float* __restrict__ T,
                                                float* __restrict__ X) {
  int bky = blockIdx.x;
  int ih = threadIdx.x & 15;
  int ag = threadIdx.x >> 4;
  const float* Tp = T + (size_t)bky * 32768 + ih * 8;

  float cd1, sd1n, cd2, sd2n;
  { float ss, cc; sincosf(PI2F * (float)ag * (1.0f / 256.0f), &ss, &cc); cd1 = cc; sd1n = -ss; }
  { float ss, cc; sincosf(PI2F * (float)(ag - 16) * (1.0f / 256.0f), &ss, &cc); cd2 = cc; sd2n = -ss; }
  float c1 = 1.0f, s1 = 0.0f, c2 = 1.0f, s2 = 0.0f;

  float xr1[4], xi1[4], xr2[4], xi2[4];
#pragma unroll
  for (int ii = 0; ii < 4; ++ii) { xr1[ii] = xi1[ii] = xr2[ii] = xi2[ii] = 0.0f; }

#pragma unroll 4
  for (int m = 0; m < 256; ++m) {
    const float4* tp4 = reinterpret_cast<const float4*>(Tp + (size_t)m * 128);
    float4 t0 = tp4[0], t1 = tp4[1];
    float tre[4] = {t0.x, t0.z, t1.x, t1.z};
    float tim[4] = {t0.y, t0.w, t1.y, t1.w};
#pragma unroll
    for (int ii = 0; ii < 4; ++ii) {
      xr1[ii] += tre[ii] * c1 - tim[ii] * s1;
      xi1[ii] += tre[ii] * s1 + tim[ii] * c1;
      xr2[ii] += tre[ii] * c2 - tim[ii] * s2;
      xi2[ii] += tre[ii] * s2 + tim[ii] * c2;
    }
    float cn;
    cn = c1 * cd1 - s1 * sd1n; s1 = c1 * sd1n + s1 * cd1; c1 = cn;
    cn = c2 * cd2 - s2 * sd2n; s2 = c2 * sd2n + s2 * cd2; c2 = cn;
  }

  float* Xp1 = X + ((size_t)bky * 32 + ag) * 128 + ih * 8;
  float* Xp2 = X + ((size_t)bky * 32 + ag + 16) * 128 + ih * 8;
  reinterpret_cast<float4*>(Xp1)[0] = make_float4(xr1[0], xi1[0], xr1[1], xi1[1]);
  reinterpret_cast<float4*>(Xp1)[1] = make_float4(xr1[2], xi1[2], xr1[3], xi1[3]);
  reinterpret_cast<float4*>(Xp2)[0] = make_float4(xr2[0], xi2[0], xr2[1], xi2[1]);
  reinterpret_cast<float4*>(Xp2)[1] = make_float4(xr2[2], xi2[2], xr2[3], xi2[3]);
}

// ---------------- K3: mode mix over i (fp32) ----------------
__global__ __launch_bounds__(256) void k3_mix(const float* __restrict__ Xg,
                                              const float* __restrict__ wT,
                                              float* __restrict__ OF) {
  int blk = blockIdx.x;
  int kyy = blk >> 5, a = blk & 31;
  __shared__ float wre[64 * 65];
  __shared__ float wim[64 * 65];
  __shared__ float xsh[16 * 128];

  const float2* wsrc = reinterpret_cast<const float2*>(wT) + (size_t)(kyy * 32 + a) * 4096;
#pragma unroll
  for (int k = 0; k < 16; ++k) {
    int p = k * 256 + (int)threadIdx.x;
    float2 v = wsrc[p];
    int i = p >> 6, o = p & 63;
    wre[i * 65 + o] = v.x;
    wim[i * 65 + o] = v.y;
  }
  {
    int bb = threadIdx.x >> 4, icn = threadIdx.x & 15;
    const float4* xsrc = reinterpret_cast<const float4*>(
        Xg + ((size_t)(bb * 16 + kyy) * 32 + a) * 128);
    float4* xdst = reinterpret_cast<float4*>(xsh + bb * 128);
    xdst[icn * 2]     = xsrc[icn * 2];
    xdst[icn * 2 + 1] = xsrc[icn * 2 + 1];
  }
  __syncthreads();

  int o = threadIdx.x & 63, bg = threadIdx.x >> 6;
#pragma unroll
  for (int bb = 0; bb < 4; ++bb) {
    int b = bg * 4 + bb;
    float ore = 0.0f, oim = 0.0f;
    for (int i = 0; i < 64; ++i) {
      float xr = xsh[b * 128 + 2 * i], xi = xsh[b * 128 + 2 * i + 1];
      float wr = wre[i * 65 + o],     wi = wim[i * 65 + o];
      ore += xr * wr - xi * wi;
      oim += xr * wi + xi * wr;
    }
    reinterpret_cast<float2*>(OF)[(((size_t)b * 16 + kyy) * 32 + a) * 64 + o] =
        make_float2(ore, oim);
  }
}

// ---------------- K4: inverse DFT over kx, fold c_ky & scale (fp32) ----------------
__global__ __launch_bounds__(256) void k4_inv_kx(const float* __restrict__ OF,
                                                 float* __restrict__ G) {
  int blk = blockIdx.x;
  int b = blk >> 4, ug = blk & 15;
  __shared__ float ofs[16384];
  __shared__ float ct[256], st[256];
  {
    float ssv, ccv;
    sincosf(PI2F * (float)threadIdx.x * (1.0f / 256.0f), &ssv, &ccv);
    ct[threadIdx.x] = ccv;
    st[threadIdx.x] = ssv;
  }
  int o = threadIdx.x & 63, us = threadIdx.x >> 6;
  int u0 = ug * 16 + us * 4;
  const float SC2 = 0.002772904280510622f;   // sqrt(256*129)/65536

  for (int chunk = 0; chunk < 4; ++chunk) {
    __syncthreads();
    const float4* src = reinterpret_cast<const float4*>(
        OF + (size_t)(b * 16 + chunk * 4) * 4096);
    float4* dst = reinterpret_cast<float4*>(ofs);
#pragma unroll
    for (int k = 0; k < 16; ++k) dst[k * 256 + threadIdx.x] = src[k * 256 + threadIdx.x];
    __syncthreads();

    float accr[4][4], acci[4][4];
#pragma unroll
    for (int du = 0; du < 4; ++du)
#pragma unroll
      for (int kyl = 0; kyl < 4; ++kyl) { accr[du][kyl] = 0.0f; acci[du][kyl] = 0.0f; }

    for (int a = 0; a < 32; ++a) {
      int kx = (a < 16) ? a : (224 + a);
      float ofr[4], ofi[4];
#pragma unroll
      for (int kyl = 0; kyl < 4; ++kyl) {
        ofr[kyl] = ofs[((kyl * 32 + a) * 64 + o) * 2];
        ofi[kyl] = ofs[((kyl * 32 + a) * 64 + o) * 2 + 1];
      }
#pragma unroll
      for (int du = 0; du < 4; ++du) {
        int t = (kx * (u0 + du)) & 255;
        float cv = ct[t], sv = st[t];
#pragma unroll
        for (int kyl = 0; kyl < 4; ++kyl) {
          accr[du][kyl] += ofr[kyl] * cv - ofi[kyl] * sv;
          acci[du][kyl] += ofr[kyl] * sv + ofi[kyl] * cv;
        }
      }
    }
#pragma unroll
    for (int du = 0; du < 4; ++du) {
      int u = u0 + du;
#pragma unroll
      for (int kyl = 0; kyl < 4; ++kyl) {
        int ky = chunk * 4 + kyl;
        float sc = SC2 * ((ky == 0) ? 1.0f : 2.0f);
        reinterpret_cast<float2*>(G)[(((size_t)b * 256 + u) * 16 + ky) * 64 + o] =
            make_float2(accr[du][kyl] * sc, acci[du][kyl] * sc);
      }
    }
  }
}

// ---------------- K5 (MFMA): Y = CS @ G'; OUT = relu(Y@W + b + Y) ----------------
// grid 4096 = (b,u), 256 thr = 4 waves; wave w owns v-rows 64w..64w+63.
// Phase A: A=CS (LDS, [v][40] bf16), B=G' (LDS, [o][40] bf16, rows 2ky=gre,
// 2ky+1=-gim), 16 MFMA -> Y tiles in acc; Y -> LDS bf16 [v][72].
// Phase B: A=Y, B=Wt (LDS, [o_out][72] bf16), C init = phaseA acc + bias.
__global__ __launch_bounds__(256) void k5_mfma(const float* __restrict__ G,
                                               const unsigned short* __restrict__ CSg,
                                               const float* __restrict__ Wg,
                                               const float* __restrict__ bias,
                                               float* __restrict__ out) {
  __shared__ unsigned short csl[256 * 40];  // 20480 B
  __shared__ unsigned short gml[64 * 40];   //  5120 B
  __shared__ unsigned short yl[256 * 72];   // 36864 B
  __shared__ unsigned short wtl[64 * 72];   //  9216 B
  __shared__ float bl[64];

  int blk = blockIdx.x;
  int b = blk >> 8, u = blk & 255;
  int tid = threadIdx.x;

  {  // stage CS: [256][32] bf16 -> [v][40]
    const unsigned int* src = reinterpret_cast<const unsigned int*>(CSg);
    unsigned int* dst = reinterpret_cast<unsigned int*>(csl);
#pragma unroll
    for (int t = 0; t < 16; ++t) {
      int idx = t * 256 + tid;              // dw in [256][16]
      dst[(idx >> 4) * 20 + (idx & 15)] = src[idx];
    }
  }
  {  // stage W transposed: Wt[o_out][o_in]
#pragma unroll
    for (int t = 0; t < 16; ++t) {
      int p = t * 256 + tid;                // p = i*64 + o
      wtl[(p & 63) * 72 + (p >> 6)] = f_to_bf16(Wg[p]);
    }
  }
  {  // stage G': row 2ky = gre, 2ky+1 = -gim (both bf16, packed dword)
    int o = tid & 63, kq = tid >> 6;
    const float2* G2 = reinterpret_cast<const float2*>(G) + ((size_t)blk * 16) * 64;
    unsigned int* gd = reinterpret_cast<unsigned int*>(gml);
#pragma unroll
    for (int q = 0; q < 4; ++q) {
      int ky = kq * 4 + q;
      float2 gv = G2[ky * 64 + o];
      gd[o * 20 + ky] = (unsigned int)f_to_bf16(gv.x) |
                        ((unsigned int)f_to_bf16(-gv.y) << 16);
    }
  }
  if (tid < 64) bl[tid] = bias[tid];
  __syncthreads();

  int lane = tid & 63, w = tid >> 6;
  int r16 = lane & 15, g4 = lane >> 4;
  int kc0 = g4 * 8;

  f32x4 z = {0.f, 0.f, 0.f, 0.f};
  f32x4 acc[4][4];

  // ---- phase A ----
  short8v af[4], bfx[4];
#pragma unroll
  for (int vt = 0; vt < 4; ++vt)
    af[vt] = *reinterpret_cast<const short8v*>(&csl[(w * 64 + vt * 16 + r16) * 40 + kc0]);
#pragma unroll
  for (int ot = 0; ot < 4; ++ot)
    bfx[ot] = *reinterpret_cast<const short8v*>(&gml[(ot * 16 + r16) * 40 + kc0]);
#pragma unroll
  for (int vt = 0; vt < 4; ++vt)
#pragma unroll
    for (int ot = 0; ot < 4; ++ot)
      acc[vt][ot] = __builtin_amdgcn_mfma_f32_16x16x32_bf16(af[vt], bfx[ot], z, 0, 0, 0);

  // Y -> LDS bf16
#pragma unroll
  for (int vt = 0; vt < 4; ++vt)
#pragma unroll
    for (int ot = 0; ot < 4; ++ot)
#pragma unroll
      for (int r = 0; r < 4; ++r)
        yl[(w * 64 + vt * 16 + g4 * 4 + r) * 72 + ot * 16 + r16] = f_to_bf16(acc[vt][ot][r]);
  __syncthreads();

  // ---- phase B: acc += bias, then += Y @ W ----
  float bv[4];
#pragma unroll
  for (int ot = 0; ot < 4; ++ot) bv[ot] = bl[ot * 16 + r16];
#pragma unroll
  for (int vt = 0; vt < 4; ++vt)
#pragma unroll
    for (int ot = 0; ot < 4; ++ot)
#pragma unroll
      for (int r = 0; r < 4; ++r) acc[vt][ot][r] += bv[ot];

#pragma unroll
  for (int ks = 0; ks < 2; ++ks) {
    int k0 = ks * 32 + kc0;
    short8v ya[4], wb[4];
#pragma unroll
    for (int vt = 0; vt < 4; ++vt)
      ya[vt] = *reinterpret_cast<const short8v*>(&yl[(w * 64 + vt * 16 + r16) * 72 + k0]);
#pragma unroll
    for (int ot = 0; ot < 4; ++ot)
      wb[ot] = *reinterpret_cast<const short8v*>(&wtl[(ot * 16 + r16) * 72 + k0]);
#pragma unroll
    for (int vt = 0; vt < 4; ++vt)
#pragma unroll
      for (int ot = 0; ot < 4; ++ot)
        acc[vt][ot] = __builtin_amdgcn_mfma_f32_16x16x32_bf16(ya[vt], wb[ot], acc[vt][ot], 0, 0, 0);
  }

  // ---- epilogue: relu + store ----
  float* ob = out + (size_t)blk * 16384;
#pragma unroll
  for (int vt = 0; vt < 4; ++vt)
#pragma unroll
    for (int r = 0; r < 4; ++r) {
      int v = w * 64 + vt * 16 + g4 * 4 + r;
      float* op = ob + (size_t)v * 64 + r16;
#pragma unroll
      for (int ot = 0; ot < 4; ++ot)
        op[ot * 16] = fmaxf(acc[vt][ot][r], 0.0f);
    }
}

extern "C" void kernel_launch(void* const* d_in, const int* in_sizes, int n_in,
                              void* d_out, int out_size, void* d_ws, size_t ws_size,
                              hipStream_t stream) {
  const float* x   = (const float*)d_in[0];
  const float* fw1 = (const float*)d_in[1];
  const float* fw2 = (const float*)d_in[2];
  const float* W   = (const float*)d_in[3];
  const float* bb  = (const float*)d_in[4];
  float* out = (float*)d_out;

  float* ws = (float*)d_ws;
  float* wT = ws;                     // 4,194,304 floats
  float* T  = ws + 4194304;           // 8,388,608 floats
  float* X  = ws + 12582912;          // 1,048,576 floats
  float* OF = ws + 13631488;          // 1,048,576 floats
  float* G  = T;                      // alias: T dead after k2
  unsigned short* Eg  = (unsigned short*)(ws + 14680064);  // 8192 u16
  unsigned short* CSg = Eg + 8192;                         // 8192 u16

  hipLaunchKernelGGL(k_tab,    dim3(1),    dim3(256), 0, stream, Eg, CSg);
  hipLaunchKernelGGL(k_wt,     dim3(256),  dim3(256), 0, stream, fw1, fw2, (float2*)wT);
  hipLaunchKernelGGL(k1_mfma,  dim3(4096), dim3(256), 0, stream, x, Eg, T);
  hipLaunchKernelGGL(k2_fwd_m, dim3(256),  dim3(256), 0, stream, T, X);
  hipLaunchKernelGGL(k3_mix,   dim3(512),  dim3(256), 0, stream, X, wT, OF);
  hipLaunchKernelGGL(k4_inv_kx,dim3(256),  dim3(256), 0, stream, OF, G);
  hipLaunchKernelGGL(k5_mfma,  dim3(4096), dim3(256), 0, stream, G, CSg, W, bb, out);
}

// Round 5
// 241.178 us; speedup vs baseline: 2.5370x; 1.0639x over previous
//
#include <hip/hip_runtime.h>
#include <hip/hip_bf16.h>

// FourierLayer2dLite on gfx950.  B=16, M=N=256, I=O=64, NM=16.
// Modes: kx in {0..15,240..255} (a: kx = a<16 ? a : 224+a), ky in [0,16).
// Pipeline:
//   k_tab: Eg[kc][n] bf16 (cos/-sin), CSg[v][kc] bf16 (cos/+sin), Wt[o][i] bf16
//   k_wt : wT[ky][a][i][o] float2
//   k1m  : Tb[b][ky][m][i] bf16x2 = (1/256) E[32x256] @ x[b,m,:,:]   (MFMA)
//   k2   : Xp[mc][b][ky][a][i] f32x2 partial DFT over m-chunk         (fp32)
//   k3   : OF[b][ky][a][o] f32x2 = sum_i (sum_mc Xp) * w              (fp32)
//   k4   : Gb[b][u][o][kc] bf16 = c_ky*SC2*(re,-im){sum_a OF e^{+i..}}(fp32->bf16)
//   k5m  : Y = CS[256x32] @ Gb';  OUT = relu(Y@W + b + Y)             (MFMA)
// MFMA 16x16x32 bf16: A[m][k]: m=lane&15,k=(lane>>4)*8+j; B[k][n]: n=lane&15;
// C/D: col=lane&15, row=(lane>>4)*4+reg.

#define PI2F 6.283185307179586f

typedef __attribute__((ext_vector_type(8))) short short8v;
typedef __attribute__((ext_vector_type(4))) float f32x4;

static __device__ __forceinline__ float bf16_to_f(unsigned short h) {
  union { unsigned int u; float f; } v; v.u = ((unsigned int)h) << 16; return v.f;
}
static __device__ __forceinline__ unsigned short f_to_bf16(float f) {
  unsigned int u = __float_as_uint(f);
  u += 0x7fffu + ((u >> 16) & 1u);   // RNE (finite values)
  return (unsigned short)(u >> 16);
}
static __device__ __forceinline__ unsigned int pack_bf16(float lo, float hi) {
  return (unsigned int)f_to_bf16(lo) | ((unsigned int)f_to_bf16(hi) << 16);
}

// ---------------- k_tab: trig + Wt tables (1 block) ----------------
__global__ __launch_bounds__(256) void k_tab(unsigned short* __restrict__ Eg,
                                             unsigned short* __restrict__ CSg,
                                             const float* __restrict__ Wg,
                                             unsigned short* __restrict__ Wtb) {
  int t = threadIdx.x;                // n or v
#pragma unroll
  for (int ky = 0; ky < 16; ++ky) {
    int idx = (ky * t) & 255;
    float ss, cc;
    sincosf(PI2F * (float)idx * (1.0f / 256.0f), &ss, &cc);
    Eg[(2 * ky) * 256 + t]     = f_to_bf16(cc);
    Eg[(2 * ky + 1) * 256 + t] = f_to_bf16(-ss);
    CSg[t * 32 + 2 * ky]       = f_to_bf16(cc);
    CSg[t * 32 + 2 * ky + 1]   = f_to_bf16(ss);
  }
#pragma unroll
  for (int k = 0; k < 16; ++k) {
    int p = k * 256 + t;              // p = i*64 + o
    Wtb[(p & 63) * 64 + (p >> 6)] = f_to_bf16(Wg[p]);
  }
}

// ---------------- K0: weight transpose ----------------
__global__ __launch_bounds__(256) void k_wt(const float* __restrict__ fw1,
                                            const float* __restrict__ fw2,
                                            float2* __restrict__ wT) {
  int a  = blockIdx.x >> 3;
  int ic = blockIdx.x & 7;
  const float* w = (a < 16) ? fw1 : fw2;
  int xx = a & 15;
#pragma unroll
  for (int k = 0; k < 2; ++k) {
    int p = k * 256 + (int)threadIdx.x;
    int i = ic * 8 + (p >> 6);
    int o = p & 63;
    const float4* s4 = reinterpret_cast<const float4*>(
        w + ((((size_t)i * 64 + o) * 16 + xx) * 16) * 2);
#pragma unroll
    for (int j = 0; j < 8; ++j) {
      float4 q = s4[j];
      wT[(((size_t)(2 * j) * 32 + a) * 64 + i) * 64 + o]     = make_float2(q.x, q.y);
      wT[(((size_t)(2 * j + 1) * 32 + a) * 64 + i) * 64 + o] = make_float2(q.z, q.w);
    }
  }
}

// ---------------- K1 (MFMA): Tb[b,ky,m,i] = (1/256) E @ x, bf16 packed ----------------
// grid 4096 = (b,m), 256 thr = 4 waves; wave w owns i-cols 16w..16w+15.
__global__ __launch_bounds__(256) void k1_mfma(const float* __restrict__ x,
                                               const unsigned short* __restrict__ Eg,
                                               unsigned int* __restrict__ Tb) {
  __shared__ unsigned short El[32 * 264];   // [kc][n], stride 264
  int bm = blockIdx.x;
  int b = bm >> 8, m = bm & 255;
  int tid = threadIdx.x;

  {
    const unsigned int* src = reinterpret_cast<const unsigned int*>(Eg);
    unsigned int* dst = reinterpret_cast<unsigned int*>(El);
#pragma unroll
    for (int t = 0; t < 16; ++t) {
      int idx = t * 256 + tid;              // dw index in [32][128]
      dst[(idx >> 7) * 132 + (idx & 127)] = src[idx];
    }
  }
  __syncthreads();

  int lane = tid & 63, w = tid >> 6;
  int r16 = lane & 15, g4 = lane >> 4;
  const float* xp = x + (size_t)bm * 16384 + (w * 16 + r16);

  f32x4 z = {0.f, 0.f, 0.f, 0.f};
  f32x4 acc0 = z, acc1 = z;

#pragma unroll
  for (int ks = 0; ks < 8; ++ks) {
    int nb = ks * 32 + g4 * 8;
    float xv[8];
#pragma unroll
    for (int j = 0; j < 8; ++j) xv[j] = xp[(size_t)(nb + j) * 64];
    short8v bfr;
#pragma unroll
    for (int j = 0; j < 8; ++j) bfr[j] = (short)f_to_bf16(xv[j]);
    short8v a0 = *reinterpret_cast<const short8v*>(&El[r16 * 264 + nb]);
    short8v a1 = *reinterpret_cast<const short8v*>(&El[(16 + r16) * 264 + nb]);
    acc0 = __builtin_amdgcn_mfma_f32_16x16x32_bf16(a0, bfr, acc0, 0, 0, 0);
    acc1 = __builtin_amdgcn_mfma_f32_16x16x32_bf16(a1, bfr, acc1, 0, 0, 0);
  }

  const float SC = 1.0f / 256.0f;
  int i = w * 16 + r16;
#pragma unroll
  for (int mt = 0; mt < 2; ++mt) {
    f32x4 av = (mt == 0) ? acc0 : acc1;
    int ky_a = mt * 8 + g4 * 2;             // rows r=0,1 -> ky_a(c0,c1); r=2,3 -> ky_a+1
    Tb[((size_t)(b * 16 + ky_a) * 256 + m) * 64 + i]       = pack_bf16(av[0] * SC, av[1] * SC);
    Tb[((size_t)(b * 16 + ky_a + 1) * 256 + m) * 64 + i]   = pack_bf16(av[2] * SC, av[3] * SC);
  }
}

// ---------------- K2: partial forward DFT over m-chunk (fp32) ----------------
// grid 1024 = (mc, bky); thread = (i-chunk of 4 complex, a-pair {ag, ag-16}).
__global__ __launch_bounds__(256) void k2_fwd_m(const unsigned int* __restrict__ Tb,
                                                float* __restrict__ Xp) {
  int bx = blockIdx.x;
  int bky = bx & 255, mc = bx >> 8;
  int m0 = mc * 64;
  int ih = threadIdx.x & 15;
  int ag = threadIdx.x >> 4;
  const uint4* Tp4 = reinterpret_cast<const uint4*>(Tb) + (size_t)bky * 4096 + ih;

  float cd1, sd1n, cd2, sd2n;
  { float ss, cc; sincosf(PI2F * (float)ag * (1.0f / 256.0f), &ss, &cc); cd1 = cc; sd1n = -ss; }
  { float ss, cc; sincosf(PI2F * (float)(ag - 16) * (1.0f / 256.0f), &ss, &cc); cd2 = cc; sd2n = -ss; }
  float c1, s1, c2, s2;
  { int t = (ag * m0) & 255; float ss, cc; sincosf(PI2F * (float)t * (1.0f / 256.0f), &ss, &cc); c1 = cc; s1 = -ss; }
  { int t = ((ag + 240) * m0) & 255; float ss, cc; sincosf(PI2F * (float)t * (1.0f / 256.0f), &ss, &cc); c2 = cc; s2 = -ss; }

  float xr1[4], xi1[4], xr2[4], xi2[4];
#pragma unroll
  for (int ii = 0; ii < 4; ++ii) { xr1[ii] = xi1[ii] = xr2[ii] = xi2[ii] = 0.0f; }

#pragma unroll 4
  for (int m = 0; m < 64; ++m) {
    uint4 q = Tp4[(size_t)(m0 + m) * 16];
    unsigned int dv[4] = {q.x, q.y, q.z, q.w};
    float tre[4], tim[4];
#pragma unroll
    for (int ii = 0; ii < 4; ++ii) {
      tre[ii] = __uint_as_float(dv[ii] << 16);
      tim[ii] = __uint_as_float(dv[ii] & 0xffff0000u);
    }
#pragma unroll
    for (int ii = 0; ii < 4; ++ii) {
      xr1[ii] += tre[ii] * c1 - tim[ii] * s1;
      xi1[ii] += tre[ii] * s1 + tim[ii] * c1;
      xr2[ii] += tre[ii] * c2 - tim[ii] * s2;
      xi2[ii] += tre[ii] * s2 + tim[ii] * c2;
    }
    float cn;
    cn = c1 * cd1 - s1 * sd1n; s1 = c1 * sd1n + s1 * cd1; c1 = cn;
    cn = c2 * cd2 - s2 * sd2n; s2 = c2 * sd2n + s2 * cd2; c2 = cn;
  }

  float* Xb = Xp + (size_t)mc * 1048576;
  float* Xp1 = Xb + ((size_t)bky * 32 + ag) * 128 + ih * 8;
  float* Xp2 = Xb + ((size_t)bky * 32 + ag + 16) * 128 + ih * 8;
  reinterpret_cast<float4*>(Xp1)[0] = make_float4(xr1[0], xi1[0], xr1[1], xi1[1]);
  reinterpret_cast<float4*>(Xp1)[1] = make_float4(xr1[2], xi1[2], xr1[3], xi1[3]);
  reinterpret_cast<float4*>(Xp2)[0] = make_float4(xr2[0], xi2[0], xr2[1], xi2[1]);
  reinterpret_cast<float4*>(Xp2)[1] = make_float4(xr2[2], xi2[2], xr2[3], xi2[3]);
}

// ---------------- K3: mode mix over i (fp32), sums 4 X partials ----------------
__global__ __launch_bounds__(256) void k3_mix(const float* __restrict__ Xp,
                                              const float* __restrict__ wT,
                                              float* __restrict__ OF) {
  int blk = blockIdx.x;
  int kyy = blk >> 5, a = blk & 31;
  __shared__ float wre[64 * 65];
  __shared__ float wim[64 * 65];
  __shared__ float xsh[16 * 128];

  const float2* wsrc = reinterpret_cast<const float2*>(wT) + (size_t)(kyy * 32 + a) * 4096;
#pragma unroll
  for (int k = 0; k < 16; ++k) {
    int p = k * 256 + (int)threadIdx.x;
    float2 v = wsrc[p];
    int i = p >> 6, o = p & 63;
    wre[i * 65 + o] = v.x;
    wim[i * 65 + o] = v.y;
  }
  {
    int bb = threadIdx.x >> 4, icn = threadIdx.x & 15;
    size_t off = ((size_t)(bb * 16 + kyy) * 32 + a) * 128;
    float4 a0 = make_float4(0.f, 0.f, 0.f, 0.f), a1 = a0;
#pragma unroll
    for (int c = 0; c < 4; ++c) {
      const float4* xsrc = reinterpret_cast<const float4*>(Xp + (size_t)c * 1048576 + off);
      float4 q0 = xsrc[icn * 2], q1 = xsrc[icn * 2 + 1];
      a0.x += q0.x; a0.y += q0.y; a0.z += q0.z; a0.w += q0.w;
      a1.x += q1.x; a1.y += q1.y; a1.z += q1.z; a1.w += q1.w;
    }
    float4* xdst = reinterpret_cast<float4*>(xsh + bb * 128);
    xdst[icn * 2]     = a0;
    xdst[icn * 2 + 1] = a1;
  }
  __syncthreads();

  int o = threadIdx.x & 63, bg = threadIdx.x >> 6;
#pragma unroll
  for (int bb = 0; bb < 4; ++bb) {
    int b = bg * 4 + bb;
    float ore = 0.0f, oim = 0.0f;
    for (int i = 0; i < 64; ++i) {
      float xr = xsh[b * 128 + 2 * i], xi = xsh[b * 128 + 2 * i + 1];
      float wr = wre[i * 65 + o],     wi = wim[i * 65 + o];
      ore += xr * wr - xi * wi;
      oim += xr * wi + xi * wr;
    }
    reinterpret_cast<float2*>(OF)[(((size_t)b * 16 + kyy) * 32 + a) * 64 + o] =
        make_float2(ore, oim);
  }
}

// ---------------- K4: inverse DFT over kx; writes Gb bf16 [b][u][o][kc] ----------------
// grid 1024 = (b, ug of 16 u, ky-chunk); folds c_ky, SC2, and -im.
__global__ __launch_bounds__(256) void k4_inv_kx(const float* __restrict__ OF,
                                                 uint4* __restrict__ Gb4) {
  int bx = blockIdx.x;
  int b = bx >> 6, ug = (bx >> 2) & 15, chunk = bx & 3;
  __shared__ float ofs[16384];         // [4ky][32a][64o] float2
  __shared__ float ct[256], st[256];
  {
    float ssv, ccv;
    sincosf(PI2F * (float)threadIdx.x * (1.0f / 256.0f), &ssv, &ccv);
    ct[threadIdx.x] = ccv;
    st[threadIdx.x] = ssv;
  }
  {
    const float4* src = reinterpret_cast<const float4*>(
        OF + ((size_t)b * 16 + chunk * 4) * 4096);
    float4* dst = reinterpret_cast<float4*>(ofs);
#pragma unroll
    for (int k = 0; k < 16; ++k) dst[k * 256 + threadIdx.x] = src[k * 256 + threadIdx.x];
  }
  __syncthreads();

  int o = threadIdx.x & 63, us = threadIdx.x >> 6;
  int u0 = ug * 16 + us * 4;
  const float SC2 = 0.002772904280510622f;   // sqrt(256*129)/65536

  float accr[4][4], acci[4][4];
#pragma unroll
  for (int du = 0; du < 4; ++du)
#pragma unroll
    for (int kyl = 0; kyl < 4; ++kyl) { accr[du][kyl] = 0.0f; acci[du][kyl] = 0.0f; }

  for (int a = 0; a < 32; ++a) {
    int kx = (a < 16) ? a : (224 + a);
    float ofr[4], ofi[4];
#pragma unroll
    for (int kyl = 0; kyl < 4; ++kyl) {
      ofr[kyl] = ofs[((kyl * 32 + a) * 64 + o) * 2];
      ofi[kyl] = ofs[((kyl * 32 + a) * 64 + o) * 2 + 1];
    }
#pragma unroll
    for (int du = 0; du < 4; ++du) {
      int t = (kx * (u0 + du)) & 255;
      float cv = ct[t], sv = st[t];
#pragma unroll
      for (int kyl = 0; kyl < 4; ++kyl) {
        accr[du][kyl] += ofr[kyl] * cv - ofi[kyl] * sv;
        acci[du][kyl] += ofr[kyl] * sv + ofi[kyl] * cv;
      }
    }
  }
#pragma unroll
  for (int du = 0; du < 4; ++du) {
    int u = u0 + du;
    unsigned int wv[4];
#pragma unroll
    for (int kyl = 0; kyl < 4; ++kyl) {
      int ky = chunk * 4 + kyl;
      float sc = SC2 * ((ky == 0) ? 1.0f : 2.0f);
      wv[kyl] = pack_bf16(accr[du][kyl] * sc, -acci[du][kyl] * sc);
    }
    uint4 pk; pk.x = wv[0]; pk.y = wv[1]; pk.z = wv[2]; pk.w = wv[3];
    Gb4[(((size_t)b * 256 + u) * 64 + o) * 4 + chunk] = pk;
  }
}

// ---------------- K5 (MFMA): Y = CS @ G'; OUT = relu(Y@W + b + Y) ----------------
// grid 4096 = (b,u), 256 thr = 4 waves; wave w owns v-rows 64w..64w+63.
// CS/Wt/bias/G read per-lane from global (L2-hot tables; G read once per block).
// Only Y round-trips LDS (bf16, [256][72]) -> 4 blocks/CU.
__global__ __launch_bounds__(256) void k5_mfma(const unsigned short* __restrict__ Gb,
                                               const unsigned short* __restrict__ CSg,
                                               const unsigned short* __restrict__ Wtb,
                                               const float* __restrict__ bias,
                                               float* __restrict__ out) {
  __shared__ unsigned short yl[256 * 72];   // 36864 B

  int blk = blockIdx.x;
  int tid = threadIdx.x;
  int lane = tid & 63, w = tid >> 6;
  int r16 = lane & 15, g4 = lane >> 4;
  int kc0 = g4 * 8;

  f32x4 z = {0.f, 0.f, 0.f, 0.f};
  f32x4 acc[4][4];

  // ---- phase A: A = CS rows v, B = G' rows kc cols o ----
  short8v af[4], bfx[4];
#pragma unroll
  for (int vt = 0; vt < 4; ++vt)
    af[vt] = *reinterpret_cast<const short8v*>(&CSg[(w * 64 + vt * 16 + r16) * 32 + kc0]);
#pragma unroll
  for (int ot = 0; ot < 4; ++ot)
    bfx[ot] = *reinterpret_cast<const short8v*>(
        &Gb[((size_t)blk * 64 + ot * 16 + r16) * 32 + kc0]);
#pragma unroll
  for (int vt = 0; vt < 4; ++vt)
#pragma unroll
    for (int ot = 0; ot < 4; ++ot)
      acc[vt][ot] = __builtin_amdgcn_mfma_f32_16x16x32_bf16(af[vt], bfx[ot], z, 0, 0, 0);

  // Y -> LDS bf16
#pragma unroll
  for (int vt = 0; vt < 4; ++vt)
#pragma unroll
    for (int ot = 0; ot < 4; ++ot)
#pragma unroll
      for (int r = 0; r < 4; ++r)
        yl[(w * 64 + vt * 16 + g4 * 4 + r) * 72 + ot * 16 + r16] = f_to_bf16(acc[vt][ot][r]);
  __syncthreads();

  // ---- phase B: acc += bias, then += Y @ W ----
#pragma unroll
  for (int ot = 0; ot < 4; ++ot) {
    float bv = bias[ot * 16 + r16];
#pragma unroll
    for (int vt = 0; vt < 4; ++vt)
#pragma unroll
      for (int r = 0; r < 4; ++r) acc[vt][ot][r] += bv;
  }

#pragma unroll
  for (int ks = 0; ks < 2; ++ks) {
    int k0 = ks * 32 + kc0;
    short8v ya[4], wb[4];
#pragma unroll
    for (int vt = 0; vt < 4; ++vt)
      ya[vt] = *reinterpret_cast<const short8v*>(&yl[(w * 64 + vt * 16 + r16) * 72 + k0]);
#pragma unroll
    for (int ot = 0; ot < 4; ++ot)
      wb[ot] = *reinterpret_cast<const short8v*>(&Wtb[(ot * 16 + r16) * 64 + k0]);
#pragma unroll
    for (int vt = 0; vt < 4; ++vt)
#pragma unroll
      for (int ot = 0; ot < 4; ++ot)
        acc[vt][ot] = __builtin_amdgcn_mfma_f32_16x16x32_bf16(ya[vt], wb[ot], acc[vt][ot], 0, 0, 0);
  }

  // ---- epilogue: relu + store ----
  float* ob = out + (size_t)blk * 16384;
#pragma unroll
  for (int vt = 0; vt < 4; ++vt)
#pragma unroll
    for (int r = 0; r < 4; ++r) {
      int v = w * 64 + vt * 16 + g4 * 4 + r;
      float* op = ob + (size_t)v * 64 + r16;
#pragma unroll
      for (int ot = 0; ot < 4; ++ot)
        op[ot * 16] = fmaxf(acc[vt][ot][r], 0.0f);
    }
}

extern "C" void kernel_launch(void* const* d_in, const int* in_sizes, int n_in,
                              void* d_out, int out_size, void* d_ws, size_t ws_size,
                              hipStream_t stream) {
  const float* x   = (const float*)d_in[0];
  const float* fw1 = (const float*)d_in[1];
  const float* fw2 = (const float*)d_in[2];
  const float* W   = (const float*)d_in[3];
  const float* bb  = (const float*)d_in[4];
  float* out = (float*)d_out;

  float* ws = (float*)d_ws;
  float* wT          = ws;                                   // 4,194,304 f (16 MB)
  unsigned int* Tb   = (unsigned int*)(ws + 4194304);        // 4,194,304 dw (16.8 MB)
  float* Xp          = ws + 8388608;                         // 4 x 1,048,576 f (16.8 MB)
  float* OF          = ws + 12582912;                        // 1,048,576 f (4.2 MB)
  unsigned int* Gb   = (unsigned int*)(ws + 13631488);       // 4,194,304 dw (16.8 MB)
  unsigned short* Eg  = (unsigned short*)(ws + 17825792);    // 8192 u16
  unsigned short* CSg = Eg + 8192;                           // 8192 u16
  unsigned short* Wtb = CSg + 8192;                          // 4096 u16

  hipLaunchKernelGGL(k_tab,    dim3(1),    dim3(256), 0, stream, Eg, CSg, W, Wtb);
  hipLaunchKernelGGL(k_wt,     dim3(256),  dim3(256), 0, stream, fw1, fw2, (float2*)wT);
  hipLaunchKernelGGL(k1_mfma,  dim3(4096), dim3(256), 0, stream, x, Eg, Tb);
  hipLaunchKernelGGL(k2_fwd_m, dim3(1024), dim3(256), 0, stream, Tb, Xp);
  hipLaunchKernelGGL(k3_mix,   dim3(512),  dim3(256), 0, stream, Xp, wT, OF);
  hipLaunchKernelGGL(k4_inv_kx,dim3(1024), dim3(256), 0, stream, OF, (uint4*)Gb);
  hipLaunchKernelGGL(k5_mfma,  dim3(4096), dim3(256), 0, stream,
                     (const unsigned short*)Gb, CSg, Wtb, bb, out);
}

// Round 6
// 233.576 us; speedup vs baseline: 2.6196x; 1.0325x over previous
//
#include <hip/hip_runtime.h>
#include <hip/hip_bf16.h>

// FourierLayer2dLite on gfx950.  B=16, M=N=256, I=O=64, NM=16.
// Modes: kx in {0..15,240..255} (a: kx = a<16 ? a : 224+a), ky in [0,16).
// Pipeline:
//   k_prep: blocks 0..255 -> wT[ky][a][i][o] f32x2; block 256 -> Eg/CSg/Wtb bf16
//   k1m  : Tb[b][ky][m][i] bf16x2 = (1/256) E[32x256] @ x[b,m,:,:]   (MFMA)
//          x staged through LDS chunks with float4 loads (coalesced 1KB/instr)
//   k2   : Xp[mc][b][ky][a][i] f32x2 partial DFT over m-chunk         (fp32)
//   k3   : OF[b][ky][a][o] f32x2 = sum_i (sum_mc Xp) * w              (fp32)
//   k4   : Gb[b][u][o][kc] bf16 = c_ky*SC2*(re,-im){sum_a OF e^{+i..}}(fp32->bf16)
//   k5m  : Y = CS[256x32] @ Gb';  OUT = relu(Y@W + b + Y)             (MFMA)
//          epilogue: wave-local LDS transpose -> float4 stores (1KB/instr)
// MFMA 16x16x32 bf16: A[m][k]: m=lane&15,k=(lane>>4)*8+j; B[k][n]: n=lane&15;
// C/D: col=lane&15, row=(lane>>4)*4+reg.

#define PI2F 6.283185307179586f

typedef __attribute__((ext_vector_type(8))) short short8v;
typedef __attribute__((ext_vector_type(4))) float f32x4;

static __device__ __forceinline__ unsigned short f_to_bf16(float f) {
  unsigned int u = __float_as_uint(f);
  u += 0x7fffu + ((u >> 16) & 1u);   // RNE (finite values)
  return (unsigned short)(u >> 16);
}
static __device__ __forceinline__ unsigned int pack_bf16(float lo, float hi) {
  return (unsigned int)f_to_bf16(lo) | ((unsigned int)f_to_bf16(hi) << 16);
}

// ---------------- k_prep: weight transpose (blocks 0..255) + tables (block 256) ----------------
__global__ __launch_bounds__(256) void k_prep(const float* __restrict__ fw1,
                                              const float* __restrict__ fw2,
                                              float2* __restrict__ wT,
                                              unsigned short* __restrict__ Eg,
                                              unsigned short* __restrict__ CSg,
                                              const float* __restrict__ Wg,
                                              unsigned short* __restrict__ Wtb) {
  int t = threadIdx.x;
  if (blockIdx.x == 256) {             // trig + Wt tables
#pragma unroll
    for (int ky = 0; ky < 16; ++ky) {
      int idx = (ky * t) & 255;
      float ss, cc;
      sincosf(PI2F * (float)idx * (1.0f / 256.0f), &ss, &cc);
      Eg[(2 * ky) * 256 + t]     = f_to_bf16(cc);
      Eg[(2 * ky + 1) * 256 + t] = f_to_bf16(-ss);
      CSg[t * 32 + 2 * ky]       = f_to_bf16(cc);
      CSg[t * 32 + 2 * ky + 1]   = f_to_bf16(ss);
    }
#pragma unroll
    for (int k = 0; k < 16; ++k) {
      int p = k * 256 + t;             // p = i*64 + o
      Wtb[(p & 63) * 64 + (p >> 6)] = f_to_bf16(Wg[p]);
    }
    return;
  }
  int a  = blockIdx.x >> 3;
  int ic = blockIdx.x & 7;
  const float* w = (a < 16) ? fw1 : fw2;
  int xx = a & 15;
#pragma unroll
  for (int k = 0; k < 2; ++k) {
    int p = k * 256 + t;
    int i = ic * 8 + (p >> 6);
    int o = p & 63;
    const float4* s4 = reinterpret_cast<const float4*>(
        w + ((((size_t)i * 64 + o) * 16 + xx) * 16) * 2);
#pragma unroll
    for (int j = 0; j < 8; ++j) {
      float4 q = s4[j];
      wT[(((size_t)(2 * j) * 32 + a) * 64 + i) * 64 + o]     = make_float2(q.x, q.y);
      wT[(((size_t)(2 * j + 1) * 32 + a) * 64 + i) * 64 + o] = make_float2(q.z, q.w);
    }
  }
}

// ---------------- K1 (MFMA): Tb[b,ky,m,i] = (1/256) E @ x, bf16 packed ----------------
// grid 4096 = (b,m), 256 thr = 4 waves; wave w owns i-cols 16w..16w+15.
// x staged via double-buffered LDS chunks (32n x 64i fp32, float4 coalesced).
__global__ __launch_bounds__(256) void k1_mfma(const float* __restrict__ x,
                                               const unsigned short* __restrict__ Eg,
                                               unsigned int* __restrict__ Tb) {
  __shared__ __align__(16) unsigned short El[32 * 264];   // [kc][n], stride 264
  __shared__ __align__(16) float xs[2][2048];             // [n_loc][i] chunks
  int bm = blockIdx.x;
  int b = bm >> 8, m = bm & 255;
  int tid = threadIdx.x;

  {
    const unsigned int* src = reinterpret_cast<const unsigned int*>(Eg);
    unsigned int* dst = reinterpret_cast<unsigned int*>(El);
#pragma unroll
    for (int t = 0; t < 16; ++t) {
      int idx = t * 256 + tid;              // dw index in [32][128]
      dst[(idx >> 7) * 132 + (idx & 127)] = src[idx];
    }
  }

  const float* xrow = x + (size_t)bm * 16384;
  int lane = tid & 63, w = tid >> 6;
  int r16 = lane & 15, g4 = lane >> 4;

  {  // stage chunk 0
    const float4* s = reinterpret_cast<const float4*>(xrow);
    float4 v0 = s[tid], v1 = s[256 + tid];
    float4* d = reinterpret_cast<float4*>(xs[0]);
    d[tid] = v0;
    d[256 + tid] = v1;
  }
  __syncthreads();

  f32x4 z = {0.f, 0.f, 0.f, 0.f};
  f32x4 acc0 = z, acc1 = z;

#pragma unroll
  for (int c = 0; c < 8; ++c) {
    int cur = c & 1;
    if (c < 7) {                       // prefetch next chunk into other buffer
      const float4* s = reinterpret_cast<const float4*>(xrow + (c + 1) * 2048);
      float4 v0 = s[tid], v1 = s[256 + tid];
      float4* d = reinterpret_cast<float4*>(xs[cur ^ 1]);
      d[tid] = v0;
      d[256 + tid] = v1;
    }
    const float* xb = &xs[cur][g4 * 8 * 64 + (w * 16 + r16)];
    float xv[8];
#pragma unroll
    for (int j = 0; j < 8; ++j) xv[j] = xb[j * 64];
    short8v bfr;
#pragma unroll
    for (int j = 0; j < 8; ++j) bfr[j] = (short)f_to_bf16(xv[j]);
    int nb = c * 32 + g4 * 8;
    short8v a0 = *reinterpret_cast<const short8v*>(&El[r16 * 264 + nb]);
    short8v a1 = *reinterpret_cast<const short8v*>(&El[(16 + r16) * 264 + nb]);
    acc0 = __builtin_amdgcn_mfma_f32_16x16x32_bf16(a0, bfr, acc0, 0, 0, 0);
    acc1 = __builtin_amdgcn_mfma_f32_16x16x32_bf16(a1, bfr, acc1, 0, 0, 0);
    __syncthreads();
  }

  const float SC = 1.0f / 256.0f;
  int i = w * 16 + r16;
#pragma unroll
  for (int mt = 0; mt < 2; ++mt) {
    f32x4 av = (mt == 0) ? acc0 : acc1;
    int ky_a = mt * 8 + g4 * 2;
    Tb[((size_t)(b * 16 + ky_a) * 256 + m) * 64 + i]     = pack_bf16(av[0] * SC, av[1] * SC);
    Tb[((size_t)(b * 16 + ky_a + 1) * 256 + m) * 64 + i] = pack_bf16(av[2] * SC, av[3] * SC);
  }
}

// ---------------- K2: partial forward DFT over m-chunk (fp32) ----------------
// grid 1024 = (mc, bky); thread = (i-chunk of 4 complex, a-pair {ag, ag-16}).
__global__ __launch_bounds__(256) void k2_fwd_m(const unsigned int* __restrict__ Tb,
                                                float* __restrict__ Xp) {
  int bx = blockIdx.x;
  int bky = bx & 255, mc = bx >> 8;
  int m0 = mc * 64;
  int ih = threadIdx.x & 15;
  int ag = threadIdx.x >> 4;
  const uint4* Tp4 = reinterpret_cast<const uint4*>(Tb) + (size_t)bky * 4096 + ih;

  float cd1, sd1n, cd2, sd2n;
  { float ss, cc; sincosf(PI2F * (float)ag * (1.0f / 256.0f), &ss, &cc); cd1 = cc; sd1n = -ss; }
  { float ss, cc; sincosf(PI2F * (float)(ag - 16) * (1.0f / 256.0f), &ss, &cc); cd2 = cc; sd2n = -ss; }
  float c1, s1, c2, s2;
  { int t = (ag * m0) & 255; float ss, cc; sincosf(PI2F * (float)t * (1.0f / 256.0f), &ss, &cc); c1 = cc; s1 = -ss; }
  { int t = ((ag + 240) * m0) & 255; float ss, cc; sincosf(PI2F * (float)t * (1.0f / 256.0f), &ss, &cc); c2 = cc; s2 = -ss; }

  float xr1[4], xi1[4], xr2[4], xi2[4];
#pragma unroll
  for (int ii = 0; ii < 4; ++ii) { xr1[ii] = xi1[ii] = xr2[ii] = xi2[ii] = 0.0f; }

#pragma unroll 4
  for (int m = 0; m < 64; ++m) {
    uint4 q = Tp4[(size_t)(m0 + m) * 16];
    unsigned int dv[4] = {q.x, q.y, q.z, q.w};
    float tre[4], tim[4];
#pragma unroll
    for (int ii = 0; ii < 4; ++ii) {
      tre[ii] = __uint_as_float(dv[ii] << 16);
      tim[ii] = __uint_as_float(dv[ii] & 0xffff0000u);
    }
#pragma unroll
    for (int ii = 0; ii < 4; ++ii) {
      xr1[ii] += tre[ii] * c1 - tim[ii] * s1;
      xi1[ii] += tre[ii] * s1 + tim[ii] * c1;
      xr2[ii] += tre[ii] * c2 - tim[ii] * s2;
      xi2[ii] += tre[ii] * s2 + tim[ii] * c2;
    }
    float cn;
    cn = c1 * cd1 - s1 * sd1n; s1 = c1 * sd1n + s1 * cd1; c1 = cn;
    cn = c2 * cd2 - s2 * sd2n; s2 = c2 * sd2n + s2 * cd2; c2 = cn;
  }

  float* Xb = Xp + (size_t)mc * 1048576;
  float* Xp1 = Xb + ((size_t)bky * 32 + ag) * 128 + ih * 8;
  float* Xp2 = Xb + ((size_t)bky * 32 + ag + 16) * 128 + ih * 8;
  reinterpret_cast<float4*>(Xp1)[0] = make_float4(xr1[0], xi1[0], xr1[1], xi1[1]);
  reinterpret_cast<float4*>(Xp1)[1] = make_float4(xr1[2], xi1[2], xr1[3], xi1[3]);
  reinterpret_cast<float4*>(Xp2)[0] = make_float4(xr2[0], xi2[0], xr2[1], xi2[1]);
  reinterpret_cast<float4*>(Xp2)[1] = make_float4(xr2[2], xi2[2], xr2[3], xi2[3]);
}

// ---------------- K3: mode mix over i (fp32), sums 4 X partials ----------------
__global__ __launch_bounds__(256) void k3_mix(const float* __restrict__ Xp,
                                              const float* __restrict__ wT,
                                              float* __restrict__ OF) {
  int blk = blockIdx.x;
  int kyy = blk >> 5, a = blk & 31;
  __shared__ float wre[64 * 65];
  __shared__ float wim[64 * 65];
  __shared__ float xsh[16 * 128];

  const float2* wsrc = reinterpret_cast<const float2*>(wT) + (size_t)(kyy * 32 + a) * 4096;
#pragma unroll
  for (int k = 0; k < 16; ++k) {
    int p = k * 256 + (int)threadIdx.x;
    float2 v = wsrc[p];
    int i = p >> 6, o = p & 63;
    wre[i * 65 + o] = v.x;
    wim[i * 65 + o] = v.y;
  }
  {
    int bb = threadIdx.x >> 4, icn = threadIdx.x & 15;
    size_t off = ((size_t)(bb * 16 + kyy) * 32 + a) * 128;
    float4 a0 = make_float4(0.f, 0.f, 0.f, 0.f), a1 = a0;
#pragma unroll
    for (int c = 0; c < 4; ++c) {
      const float4* xsrc = reinterpret_cast<const float4*>(Xp + (size_t)c * 1048576 + off);
      float4 q0 = xsrc[icn * 2], q1 = xsrc[icn * 2 + 1];
      a0.x += q0.x; a0.y += q0.y; a0.z += q0.z; a0.w += q0.w;
      a1.x += q1.x; a1.y += q1.y; a1.z += q1.z; a1.w += q1.w;
    }
    float4* xdst = reinterpret_cast<float4*>(xsh + bb * 128);
    xdst[icn * 2]     = a0;
    xdst[icn * 2 + 1] = a1;
  }
  __syncthreads();

  int o = threadIdx.x & 63, bg = threadIdx.x >> 6;
#pragma unroll
  for (int bb = 0; bb < 4; ++bb) {
    int b = bg * 4 + bb;
    float ore = 0.0f, oim = 0.0f;
    for (int i = 0; i < 64; ++i) {
      float xr = xsh[b * 128 + 2 * i], xi = xsh[b * 128 + 2 * i + 1];
      float wr = wre[i * 65 + o],     wi = wim[i * 65 + o];
      ore += xr * wr - xi * wi;
      oim += xr * wi + xi * wr;
    }
    reinterpret_cast<float2*>(OF)[(((size_t)b * 16 + kyy) * 32 + a) * 64 + o] =
        make_float2(ore, oim);
  }
}

// ---------------- K4: inverse DFT over kx; writes Gb bf16 [b][u][o][kc] ----------------
// grid 1024 = (b, ug of 16 u, ky-chunk); folds c_ky, SC2, and -im.
__global__ __launch_bounds__(256) void k4_inv_kx(const float* __restrict__ OF,
                                                 uint4* __restrict__ Gb4) {
  int bx = blockIdx.x;
  int b = bx >> 6, ug = (bx >> 2) & 15, chunk = bx & 3;
  __shared__ float ofs[16384];         // [4ky][32a][64o] float2
  __shared__ float ct[256], st[256];
  {
    float ssv, ccv;
    sincosf(PI2F * (float)threadIdx.x * (1.0f / 256.0f), &ssv, &ccv);
    ct[threadIdx.x] = ccv;
    st[threadIdx.x] = ssv;
  }
  {
    const float4* src = reinterpret_cast<const float4*>(
        OF + ((size_t)b * 16 + chunk * 4) * 4096);
    float4* dst = reinterpret_cast<float4*>(ofs);
#pragma unroll
    for (int k = 0; k < 16; ++k) dst[k * 256 + threadIdx.x] = src[k * 256 + threadIdx.x];
  }
  __syncthreads();

  int o = threadIdx.x & 63, us = threadIdx.x >> 6;
  int u0 = ug * 16 + us * 4;
  const float SC2 = 0.002772904280510622f;   // sqrt(256*129)/65536

  float accr[4][4], acci[4][4];
#pragma unroll
  for (int du = 0; du < 4; ++du)
#pragma unroll
    for (int kyl = 0; kyl < 4; ++kyl) { accr[du][kyl] = 0.0f; acci[du][kyl] = 0.0f; }

  for (int a = 0; a < 32; ++a) {
    int kx = (a < 16) ? a : (224 + a);
    float ofr[4], ofi[4];
#pragma unroll
    for (int kyl = 0; kyl < 4; ++kyl) {
      ofr[kyl] = ofs[((kyl * 32 + a) * 64 + o) * 2];
      ofi[kyl] = ofs[((kyl * 32 + a) * 64 + o) * 2 + 1];
    }
#pragma unroll
    for (int du = 0; du < 4; ++du) {
      int t = (kx * (u0 + du)) & 255;
      float cv = ct[t], sv = st[t];
#pragma unroll
      for (int kyl = 0; kyl < 4; ++kyl) {
        accr[du][kyl] += ofr[kyl] * cv - ofi[kyl] * sv;
        acci[du][kyl] += ofr[kyl] * sv + ofi[kyl] * cv;
      }
    }
  }
#pragma unroll
  for (int du = 0; du < 4; ++du) {
    int u = u0 + du;
    unsigned int wv[4];
#pragma unroll
    for (int kyl = 0; kyl < 4; ++kyl) {
      int ky = chunk * 4 + kyl;
      float sc = SC2 * ((ky == 0) ? 1.0f : 2.0f);
      wv[kyl] = pack_bf16(accr[du][kyl] * sc, -acci[du][kyl] * sc);
    }
    uint4 pk; pk.x = wv[0]; pk.y = wv[1]; pk.z = wv[2]; pk.w = wv[3];
    Gb4[(((size_t)b * 256 + u) * 64 + o) * 4 + chunk] = pk;
  }
}

// ---------------- K5 (MFMA): Y = CS @ G'; OUT = relu(Y@W + b + Y) ----------------
// grid 4096 = (b,u), 256 thr = 4 waves; wave w owns v-rows 64w..64w+63.
// All yl traffic is wave-local (rows w*64..) -> NO barriers. Epilogue transposes
// each 16x64 tile through the wave's own yl region -> float4 stores (1KB/instr).
__global__ __launch_bounds__(256) void k5_mfma(const unsigned short* __restrict__ Gb,
                                               const unsigned short* __restrict__ CSg,
                                               const unsigned short* __restrict__ Wtb,
                                               const float* __restrict__ bias,
                                               float* __restrict__ out) {
  __shared__ __align__(16) unsigned short yl[256 * 72];   // 36864 B

  int blk = blockIdx.x;
  int tid = threadIdx.x;
  int lane = tid & 63, w = tid >> 6;
  int r16 = lane & 15, g4 = lane >> 4;
  int kc0 = g4 * 8;

  f32x4 z = {0.f, 0.f, 0.f, 0.f};
  f32x4 acc[4][4];

  // ---- phase A: A = CS rows v, B = G' rows kc cols o ----
  short8v af[4], bfx[4];
#pragma unroll
  for (int vt = 0; vt < 4; ++vt)
    af[vt] = *reinterpret_cast<const short8v*>(&CSg[(w * 64 + vt * 16 + r16) * 32 + kc0]);
#pragma unroll
  for (int ot = 0; ot < 4; ++ot)
    bfx[ot] = *reinterpret_cast<const short8v*>(
        &Gb[((size_t)blk * 64 + ot * 16 + r16) * 32 + kc0]);
#pragma unroll
  for (int vt = 0; vt < 4; ++vt)
#pragma unroll
    for (int ot = 0; ot < 4; ++ot)
      acc[vt][ot] = __builtin_amdgcn_mfma_f32_16x16x32_bf16(af[vt], bfx[ot], z, 0, 0, 0);

  // Y -> LDS bf16 (own-wave rows only)
#pragma unroll
  for (int vt = 0; vt < 4; ++vt)
#pragma unroll
    for (int ot = 0; ot < 4; ++ot)
#pragma unroll
      for (int r = 0; r < 4; ++r)
        yl[(w * 64 + vt * 16 + g4 * 4 + r) * 72 + ot * 16 + r16] = f_to_bf16(acc[vt][ot][r]);

  // ---- phase B: acc += bias, then += Y @ W ----
#pragma unroll
  for (int ot = 0; ot < 4; ++ot) {
    float bv = bias[ot * 16 + r16];
#pragma unroll
    for (int vt = 0; vt < 4; ++vt)
#pragma unroll
      for (int r = 0; r < 4; ++r) acc[vt][ot][r] += bv;
  }

#pragma unroll
  for (int ks = 0; ks < 2; ++ks) {
    int k0 = ks * 32 + kc0;
    short8v ya[4], wb[4];
#pragma unroll
    for (int vt = 0; vt < 4; ++vt)
      ya[vt] = *reinterpret_cast<const short8v*>(&yl[(w * 64 + vt * 16 + r16) * 72 + k0]);
#pragma unroll
    for (int ot = 0; ot < 4; ++ot)
      wb[ot] = *reinterpret_cast<const short8v*>(&Wtb[(ot * 16 + r16) * 64 + k0]);
#pragma unroll
    for (int vt = 0; vt < 4; ++vt)
#pragma unroll
      for (int ot = 0; ot < 4; ++ot)
        acc[vt][ot] = __builtin_amdgcn_mfma_f32_16x16x32_bf16(ya[vt], wb[ot], acc[vt][ot], 0, 0, 0);
  }

  // ---- epilogue: relu -> wave-local LDS transpose -> coalesced float4 stores ----
  float* ob = out + (size_t)blk * 16384;
  float* tw = reinterpret_cast<float*>(&yl[w * 4608]);   // own 9216B region, reuse
#pragma unroll
  for (int vt = 0; vt < 4; ++vt) {
#pragma unroll
    for (int ot = 0; ot < 4; ++ot)
#pragma unroll
      for (int r = 0; r < 4; ++r)
        tw[(g4 * 4 + r) * 68 + ot * 16 + r16] = fmaxf(acc[vt][ot][r], 0.0f);
    float* obase = ob + (size_t)(w * 64 + vt * 16) * 64;
#pragma unroll
    for (int q = 0; q < 4; ++q) {
      float4 vv = *reinterpret_cast<const float4*>(
          &tw[(q * 4 + (lane >> 4)) * 68 + (lane & 15) * 4]);
      *reinterpret_cast<float4*>(&obase[q * 256 + lane * 4]) = vv;
    }
  }
}

extern "C" void kernel_launch(void* const* d_in, const int* in_sizes, int n_in,
                              void* d_out, int out_size, void* d_ws, size_t ws_size,
                              hipStream_t stream) {
  const float* x   = (const float*)d_in[0];
  const float* fw1 = (const float*)d_in[1];
  const float* fw2 = (const float*)d_in[2];
  const float* W   = (const float*)d_in[3];
  const float* bb  = (const float*)d_in[4];
  float* out = (float*)d_out;

  float* ws = (float*)d_ws;
  float* wT          = ws;                                   // 4,194,304 f (16 MB)
  unsigned int* Tb   = (unsigned int*)(ws + 4194304);        // 4,194,304 dw (16.8 MB)
  float* Xp          = ws + 8388608;                         // 4 x 1,048,576 f (16.8 MB)
  float* OF          = ws + 12582912;                        // 1,048,576 f (4.2 MB)
  unsigned int* Gb   = (unsigned int*)(ws + 13631488);       // 4,194,304 dw (16.8 MB)
  unsigned short* Eg  = (unsigned short*)(ws + 17825792);    // 8192 u16
  unsigned short* CSg = Eg + 8192;                           // 8192 u16
  unsigned short* Wtb = CSg + 8192;                          // 4096 u16

  hipLaunchKernelGGL(k_prep,   dim3(257),  dim3(256), 0, stream,
                     fw1, fw2, (float2*)wT, Eg, CSg, W, Wtb);
  hipLaunchKernelGGL(k1_mfma,  dim3(4096), dim3(256), 0, stream, x, Eg, Tb);
  hipLaunchKernelGGL(k2_fwd_m, dim3(1024), dim3(256), 0, stream, Tb, Xp);
  hipLaunchKernelGGL(k3_mix,   dim3(512),  dim3(256), 0, stream, Xp, wT, OF);
  hipLaunchKernelGGL(k4_inv_kx,dim3(1024), dim3(256), 0, stream, OF, (uint4*)Gb);
  hipLaunchKernelGGL(k5_mfma,  dim3(4096), dim3(256), 0, stream,
                     (const unsigned short*)Gb, CSg, Wtb, bb, out);
}